// Round 1
// 246.726 us; speedup vs baseline: 1.0150x; 1.0150x over previous
//
#include <hip/hip_runtime.h>
#include <math.h>
#include <stdint.h>

typedef __bf16 bf16_t;
typedef __bf16 bf16x2 __attribute__((ext_vector_type(2)));
typedef __bf16 bf16x4 __attribute__((ext_vector_type(4)));
typedef __bf16 bf16x8 __attribute__((ext_vector_type(8)));
typedef float f32x4 __attribute__((ext_vector_type(4)));

#define NB   32
#define SEQ  2048
#define HD   128
#define SCALE 0.08838834764831845f
#define LOG2E 1.4426950408889634f

__device__ __forceinline__ float fast_exp2(float x) {
#if __has_builtin(__builtin_amdgcn_exp2f)
  return __builtin_amdgcn_exp2f(x);
#else
  return exp2f(x);
#endif
}

// ============================ prep kernel =================================
// blocks 0..2047:    Kb = bf16(K)                  (Q is converted in fa6)
// blocks 2048..4095: Vt = bf16(V) transposed [B][D][S], conflict-free f32 tile
__global__ __launch_bounds__(256) void prep_kernel(
    const float* __restrict__ K, const float* __restrict__ V,
    bf16_t* __restrict__ Kb, bf16_t* __restrict__ Vt)
{
  const int b = blockIdx.x;
  const int tid = threadIdx.x;
  if (b < 2048) {
    size_t base4 = (size_t)b * 1024;
#pragma unroll
    for (int i = 0; i < 4; ++i) {
      size_t idx = base4 + tid + i * 256;
      float4 x = ((const float4*)K)[idx];
      bf16x4 y;
      y[0] = (bf16_t)x.x; y[1] = (bf16_t)x.y;
      y[2] = (bf16_t)x.z; y[3] = (bf16_t)x.w;
      ((bf16x4*)Kb)[idx] = y;
    }
  } else {
    // f32 tile, stride 65: word(s,d) = (65*s + d) % 32 = (s + d) % 32.
    // Writes: lanes cover (t>>4) + 4*dq = 0..63 distinct -> 2 lanes/bank (free).
    // Reads (per j): lanes cover d' + 8*sg = 0..63 distinct -> 2 lanes/bank (free).
    __shared__ float tile[64][65];  // 16.6 KB
    const int bt = b - 2048;
    const int batch = bt >> 6;
    const int rem = bt & 63;
    const int s0 = (rem >> 1) * 64;
    const int d0 = (rem & 1) * 64;
#pragma unroll
    for (int i = 0; i < 4; ++i) {
      int e = tid + i * 256;
      int s = e >> 4, dq = e & 15;
      float4 x = *(const float4*)&V[((size_t)batch * SEQ + s0 + s) * HD + d0 + dq * 4];
      tile[s][dq * 4 + 0] = x.x;
      tile[s][dq * 4 + 1] = x.y;
      tile[s][dq * 4 + 2] = x.z;
      tile[s][dq * 4 + 3] = x.w;
    }
    __syncthreads();
#pragma unroll
    for (int i = 0; i < 2; ++i) {
      int g = tid + i * 256;
      int d = g >> 3, sg = g & 7;
      bf16x8 w;
#pragma unroll
      for (int j = 0; j < 8; ++j) w[j] = (bf16_t)tile[sg * 8 + j][d];
      *(bf16x8*)&Vt[((size_t)batch * HD + d0 + d) * SEQ + s0 + sg * 8] = w;
    }
  }
}

// ============================ main kernel =================================
// fa6 = fa5 core + (a) fp32 Q read with SCALE*LOG2E folded (exp2 softmax),
// (b) defer-max rescale skip (THR=8 in log2 units, P<=256),
// (c) V fragments hoisted to registers before softmax,
// (d) s_setprio around MFMA clusters.
__global__ __launch_bounds__(256) void fa6_kernel(
    const float* __restrict__ Q, const bf16_t* __restrict__ Kbf,
    const bf16_t* __restrict__ Vt, float* __restrict__ O)
{
  __shared__ __attribute__((aligned(16))) bf16_t Ksw[2][64 * 128];   // 16KB x2
  __shared__ __attribute__((aligned(16))) bf16_t Vsw[2][128 * 64];   // 16KB x2
  __shared__ __attribute__((aligned(16))) bf16_t Psh[4][16][72];     // 9KB

  const int tid  = threadIdx.x;
  const int lane = tid & 63;
  const int wq   = tid >> 6;
  const int quad = lane >> 4;
  const int l15  = lane & 15;

  const int batch = blockIdx.x >> 5;
  const int qt    = blockIdx.x & 31;

  const float*  Qb = Q   + ((size_t)batch * SEQ + qt * 64) * HD;
  const bf16_t* Kb = Kbf + (size_t)batch * SEQ * HD;
  const bf16_t* Vb = Vt  + (size_t)batch * HD * SEQ;
  float*        Ob = O   + ((size_t)batch * SEQ + qt * 64) * HD;

  // ---- Q fragments from fp32, scale*log2(e) folded in ----
  bf16x8 aq[4];
  {
    const int qrow = wq * 16 + l15;
    const float qs = SCALE * LOG2E;
#pragma unroll
    for (int kf = 0; kf < 4; ++kf) {
      const float* qp = Qb + (size_t)qrow * HD + kf * 32 + quad * 8;
      float4 x0 = *(const float4*)qp;
      float4 x1 = *(const float4*)(qp + 4);
      bf16x8 a;
      a[0] = (bf16_t)(x0.x * qs); a[1] = (bf16_t)(x0.y * qs);
      a[2] = (bf16_t)(x0.z * qs); a[3] = (bf16_t)(x0.w * qs);
      a[4] = (bf16_t)(x1.x * qs); a[5] = (bf16_t)(x1.y * qs);
      a[6] = (bf16_t)(x1.z * qs); a[7] = (bf16_t)(x1.w * qs);
      aq[kf] = a;
    }
  }

  f32x4 o[8];
#pragma unroll
  for (int t = 0; t < 8; ++t) { o[t][0]=0.f; o[t][1]=0.f; o[t][2]=0.f; o[t][3]=0.f; }
  float m_r = -INFINITY, l_r = 0.0f;

  // ---- DMA staging: each wave stages 16 K-rows and 32 V-rows ----
  auto stage = [&](int buf, int kb) {
#pragma unroll
    for (int i = 0; i < 4; ++i) {
      int row = wq * 16 + i * 4 + (lane >> 4);
      int gk = (lane & 15) ^ (row & 15);
      const bf16_t* gp = Kb + (size_t)(kb + row) * HD + gk * 8;
      __builtin_amdgcn_global_load_lds(
          (const __attribute__((address_space(1))) void*)gp,
          (__attribute__((address_space(3))) void*)&Ksw[buf][(wq * 16 + i * 4) * 128],
          16, 0, 0);
    }
#pragma unroll
    for (int i = 0; i < 4; ++i) {
      int d = wq * 32 + i * 8 + (lane >> 3);
      int gv = (lane & 7) ^ (d & 7);
      const bf16_t* gp = Vb + (size_t)d * SEQ + kb + gv * 8;
      __builtin_amdgcn_global_load_lds(
          (const __attribute__((address_space(1))) void*)gp,
          (__attribute__((address_space(3))) void*)&Vsw[buf][(wq * 32 + i * 8) * 64],
          16, 0, 0);
    }
  };

  stage(0, 0);

  for (int it = 0; it < SEQ / 64; ++it) {
    __syncthreads();  // drains own DMA (vmcnt0 before barrier) + prior LDS reads
    if (it + 1 < SEQ / 64) stage((it + 1) & 1, (it + 1) * 64);

    const bf16_t* Ks = &Ksw[it & 1][0];
    const bf16_t* Vs = &Vsw[it & 1][0];

    // ---- S^T = K Q^T (scores in log2 units) ----
    f32x4 s[4];
#pragma unroll
    for (int ct = 0; ct < 4; ++ct) { s[ct][0]=0.f; s[ct][1]=0.f; s[ct][2]=0.f; s[ct][3]=0.f; }
    __builtin_amdgcn_s_setprio(1);
#pragma unroll
    for (int kf = 0; kf < 4; ++kf)
#pragma unroll
      for (int ct = 0; ct < 4; ++ct) {
        int row = ct * 16 + l15;
        bf16x8 ak = *(const bf16x8*)&Ks[row * 128 + (((kf * 4 + quad) ^ l15) * 8)];
        s[ct] = __builtin_amdgcn_mfma_f32_16x16x32_bf16(ak, aq[kf], s[ct], 0, 0, 0);
      }
    __builtin_amdgcn_s_setprio(0);

    // ---- row max (per-q-row, uniform across the 4 lanes of each row) ----
    float mx = s[0][0];
#pragma unroll
    for (int ct = 0; ct < 4; ++ct)
#pragma unroll
      for (int r = 0; r < 4; ++r) mx = fmaxf(mx, s[ct][r]);
    mx = fmaxf(mx, __shfl_xor(mx, 16));
    mx = fmaxf(mx, __shfl_xor(mx, 32));

    // ---- hoist V fragments: LDS reads overlap the softmax VALU chain ----
    bf16x8 av0[8], av1[8];
#pragma unroll
    for (int t = 0; t < 8; ++t) {
      const int d = t * 16 + l15;
      av0[t] = *(const bf16x8*)&Vs[d * 64 + ((quad ^ (l15 & 7)) * 8)];
      av1[t] = *(const bf16x8*)&Vs[d * 64 + (((4 + quad) ^ (l15 & 7)) * 8)];
    }

    // ---- defer-max: skip rescale unless max grew by > 8 (P bounded by 256) ----
    if (!__all(mx <= m_r + 8.0f)) {
      const float mnew = fmaxf(m_r, mx);
      const float alpha = fast_exp2(m_r - mnew);
      m_r = mnew;
      l_r *= alpha;
#pragma unroll
      for (int t = 0; t < 8; ++t) {
        o[t][0]*=alpha; o[t][1]*=alpha; o[t][2]*=alpha; o[t][3]*=alpha;
      }
    }

    // ---- P = exp2(S - m), row sum ----
    float ls = 0.f;
#pragma unroll
    for (int ct = 0; ct < 4; ++ct)
#pragma unroll
      for (int r = 0; r < 4; ++r) {
        float p = fast_exp2(s[ct][r] - m_r);
        s[ct][r] = p; ls += p;
      }

    // ---- P round-trip through Psh ----
#pragma unroll
    for (int ct = 0; ct < 4; ++ct) {
      bf16x4 pp;
      pp[0]=(bf16_t)s[ct][0]; pp[1]=(bf16_t)s[ct][1];
      pp[2]=(bf16_t)s[ct][2]; pp[3]=(bf16_t)s[ct][3];
      *(bf16x4*)&Psh[wq][l15][ct * 16 + quad * 4] = pp;
    }
    ls += __shfl_xor(ls, 16);
    ls += __shfl_xor(ls, 32);
    l_r += ls;
    asm volatile("s_waitcnt lgkmcnt(0)" ::: "memory");
    bf16x8 ap0 = *(const bf16x8*)&Psh[wq][l15][quad * 8];
    bf16x8 ap1 = *(const bf16x8*)&Psh[wq][l15][32 + quad * 8];

    // ---- O^T += V^T P^T (V fragments already in registers) ----
    __builtin_amdgcn_s_setprio(1);
#pragma unroll
    for (int t = 0; t < 8; ++t) {
      o[t] = __builtin_amdgcn_mfma_f32_16x16x32_bf16(av0[t], ap0, o[t], 0, 0, 0);
      o[t] = __builtin_amdgcn_mfma_f32_16x16x32_bf16(av1[t], ap1, o[t], 0, 0, 0);
    }
    __builtin_amdgcn_s_setprio(0);
  }

  // ---- epilogue ----
  float inv = 1.0f / l_r;
  const int qrow = wq * 16 + l15;
#pragma unroll
  for (int t = 0; t < 8; ++t) {
    float4 w;
    w.x = o[t][0]*inv; w.y = o[t][1]*inv; w.z = o[t][2]*inv; w.w = o[t][3]*inv;
    *(float4*)&Ob[(size_t)qrow * HD + t * 16 + quad * 4] = w;
  }
}

// ===================== fallback (proven R2 kernel) ========================
#define BM   64
#define BN   64
#define KPAD 8
#define VPAD 8
#define PPAD 8

__global__ __launch_bounds__(256) void fa_fallback(
    const float* __restrict__ Q, const float* __restrict__ K,
    const float* __restrict__ V, float* __restrict__ O)
{
  __shared__ __attribute__((aligned(16))) bf16_t Ksh[BN][HD + KPAD];
  __shared__ __attribute__((aligned(16))) bf16_t Vsh[HD][BN + VPAD];
  __shared__ __attribute__((aligned(16))) bf16_t Psh[4][16][BN + PPAD];

  const int tid = threadIdx.x;
  const int lane = tid & 63;
  const int wq = tid >> 6;
  const int quad = lane >> 4;
  const int l15 = lane & 15;
  const int bid = blockIdx.x;
  const int batch = bid >> 5;
  const int qt = bid & 31;

  const float* Qb = Q + (size_t)batch * SEQ * HD + (size_t)qt * BM * HD;
  const float* Kb = K + (size_t)batch * SEQ * HD;
  const float* Vb = V + (size_t)batch * SEQ * HD;
  float* Ob = O + (size_t)batch * SEQ * HD + (size_t)qt * BM * HD;

  bf16x8 aq[4];
  {
    const int qrow = wq * 16 + l15;
#pragma unroll
    for (int kf = 0; kf < 4; ++kf) {
      const float* qp = Qb + (size_t)qrow * HD + kf * 32 + quad * 8;
      float4 x0 = *(const float4*)(qp);
      float4 x1 = *(const float4*)(qp + 4);
      bf16x8 a;
      a[0] = (bf16_t)(x0.x * SCALE); a[1] = (bf16_t)(x0.y * SCALE);
      a[2] = (bf16_t)(x0.z * SCALE); a[3] = (bf16_t)(x0.w * SCALE);
      a[4] = (bf16_t)(x1.x * SCALE); a[5] = (bf16_t)(x1.y * SCALE);
      a[6] = (bf16_t)(x1.z * SCALE); a[7] = (bf16_t)(x1.w * SCALE);
      aq[kf] = a;
    }
  }

  f32x4 o[8];
#pragma unroll
  for (int t = 0; t < 8; ++t) { o[t][0]=0.f; o[t][1]=0.f; o[t][2]=0.f; o[t][3]=0.f; }
  float m_r = -INFINITY, l_r = 0.0f;
  const int vkp = (tid & 31) * 2;
  const int vg = tid >> 5;
  float4 kreg[8], vreg[8];

#pragma unroll
  for (int i = 0; i < 8; ++i) {
    int v = tid + i * 256, row = v >> 5, c4 = (v & 31) * 4;
    kreg[i] = *(const float4*)(Kb + (size_t)row * HD + c4);
  }
#pragma unroll
  for (int i = 0; i < 4; ++i) {
    int d0 = (vg + i * 8) * 4;
    const float* vp0 = Vb + (size_t)vkp * HD + d0;
    vreg[2 * i] = *(const float4*)vp0;
    vreg[2 * i + 1] = *(const float4*)(vp0 + HD);
  }

  for (int kb = 0; kb < SEQ; kb += BN) {
    __syncthreads();
#pragma unroll
    for (int i = 0; i < 8; ++i) {
      int v = tid + i * 256, row = v >> 5, c4 = (v & 31) * 4;
      float4 kv = kreg[i];
      bf16x4 kk;
      kk[0]=(bf16_t)kv.x; kk[1]=(bf16_t)kv.y; kk[2]=(bf16_t)kv.z; kk[3]=(bf16_t)kv.w;
      *(bf16x4*)&Ksh[row][c4] = kk;
    }
#pragma unroll
    for (int i = 0; i < 4; ++i) {
      int d0 = (vg + i * 8) * 4;
      float4 a0 = vreg[2 * i], a1 = vreg[2 * i + 1];
      bf16x2 p0; p0[0]=(bf16_t)a0.x; p0[1]=(bf16_t)a1.x;
      bf16x2 p1; p1[0]=(bf16_t)a0.y; p1[1]=(bf16_t)a1.y;
      bf16x2 p2; p2[0]=(bf16_t)a0.z; p2[1]=(bf16_t)a1.z;
      bf16x2 p3; p3[0]=(bf16_t)a0.w; p3[1]=(bf16_t)a1.w;
      *(bf16x2*)&Vsh[d0 + 0][vkp] = p0;
      *(bf16x2*)&Vsh[d0 + 1][vkp] = p1;
      *(bf16x2*)&Vsh[d0 + 2][vkp] = p2;
      *(bf16x2*)&Vsh[d0 + 3][vkp] = p3;
    }
    __syncthreads();

    const int kbn = kb + BN;
    if (kbn < SEQ) {
#pragma unroll
      for (int i = 0; i < 8; ++i) {
        int v = tid + i * 256, row = v >> 5, c4 = (v & 31) * 4;
        kreg[i] = *(const float4*)(Kb + (size_t)(kbn + row) * HD + c4);
      }
#pragma unroll
      for (int i = 0; i < 4; ++i) {
        int d0 = (vg + i * 8) * 4;
        const float* vp0 = Vb + (size_t)(kbn + vkp) * HD + d0;
        vreg[2 * i] = *(const float4*)vp0;
        vreg[2 * i + 1] = *(const float4*)(vp0 + HD);
      }
    }

    f32x4 s[4];
#pragma unroll
    for (int ct = 0; ct < 4; ++ct) { s[ct][0]=0.f; s[ct][1]=0.f; s[ct][2]=0.f; s[ct][3]=0.f; }
#pragma unroll
    for (int kf = 0; kf < 4; ++kf)
#pragma unroll
      for (int ct = 0; ct < 4; ++ct) {
        bf16x8 ak = *(const bf16x8*)&Ksh[ct * 16 + l15][kf * 32 + quad * 8];
        s[ct] = __builtin_amdgcn_mfma_f32_16x16x32_bf16(ak, aq[kf], s[ct], 0, 0, 0);
      }

    float mx = s[0][0];
#pragma unroll
    for (int ct = 0; ct < 4; ++ct)
#pragma unroll
      for (int r = 0; r < 4; ++r) mx = fmaxf(mx, s[ct][r]);
    mx = fmaxf(mx, __shfl_xor(mx, 16));
    mx = fmaxf(mx, __shfl_xor(mx, 32));
    float mnew = fmaxf(m_r, mx);
    float alpha = __expf(m_r - mnew);
    m_r = mnew;
    float ls = 0.f;
#pragma unroll
    for (int ct = 0; ct < 4; ++ct)
#pragma unroll
      for (int r = 0; r < 4; ++r) {
        float p = __expf(s[ct][r] - mnew);
        s[ct][r] = p; ls += p;
      }
    ls += __shfl_xor(ls, 16);
    ls += __shfl_xor(ls, 32);
    l_r = l_r * alpha + ls;

#pragma unroll
    for (int ct = 0; ct < 4; ++ct) {
      bf16x4 pp;
      pp[0]=(bf16_t)s[ct][0]; pp[1]=(bf16_t)s[ct][1];
      pp[2]=(bf16_t)s[ct][2]; pp[3]=(bf16_t)s[ct][3];
      *(bf16x4*)&Psh[wq][l15][ct * 16 + quad * 4] = pp;
    }
    asm volatile("s_waitcnt lgkmcnt(0)" ::: "memory");
    bf16x8 ap0 = *(const bf16x8*)&Psh[wq][l15][quad * 8];
    bf16x8 ap1 = *(const bf16x8*)&Psh[wq][l15][32 + quad * 8];

#pragma unroll
    for (int t = 0; t < 8; ++t) {
      o[t][0]*=alpha; o[t][1]*=alpha; o[t][2]*=alpha; o[t][3]*=alpha;
    }
#pragma unroll
    for (int t = 0; t < 8; ++t) {
      bf16x8 av0 = *(const bf16x8*)&Vsh[t * 16 + l15][quad * 8];
      o[t] = __builtin_amdgcn_mfma_f32_16x16x32_bf16(av0, ap0, o[t], 0, 0, 0);
      bf16x8 av1 = *(const bf16x8*)&Vsh[t * 16 + l15][32 + quad * 8];
      o[t] = __builtin_amdgcn_mfma_f32_16x16x32_bf16(av1, ap1, o[t], 0, 0, 0);
    }
  }

  float inv = 1.0f / l_r;
  const int qrow = wq * 16 + l15;
#pragma unroll
  for (int t = 0; t < 8; ++t) {
    float4 w;
    w.x = o[t][0]*inv; w.y = o[t][1]*inv; w.z = o[t][2]*inv; w.w = o[t][3]*inv;
    *(float4*)&Ob[(size_t)qrow * HD + t * 16 + quad * 4] = w;
  }
}

extern "C" void kernel_launch(void* const* d_in, const int* in_sizes, int n_in,
                              void* d_out, int out_size, void* d_ws, size_t ws_size,
                              hipStream_t stream) {
  const float* q = (const float*)d_in[0];
  const float* k = (const float*)d_in[1];
  const float* v = (const float*)d_in[2];
  float* out = (float*)d_out;

  const size_t elems = (size_t)NB * SEQ * HD;          // 8388608
  const size_t need = elems * 2 * 2;                   // Kb + Vt bf16 = 32 MiB

  if (ws_size >= need) {
    bf16_t* Kb = (bf16_t*)d_ws;
    bf16_t* Vt = Kb + elems;
    prep_kernel<<<4096, 256, 0, stream>>>(k, v, Kb, Vt);
    fa6_kernel<<<NB * (SEQ / 64), 256, 0, stream>>>(q, Kb, Vt, out);
  } else {
    fa_fallback<<<NB * (SEQ / BM), 256, 0, stream>>>(q, k, v, out);
  }
}